// Round 12
// baseline (151.219 us; speedup 1.0000x reference)
//
#include <hip/hip_runtime.h>
#include <hip/hip_bf16.h>

typedef __attribute__((ext_vector_type(8))) short short8;
typedef __attribute__((ext_vector_type(4))) float f32x4;
typedef __attribute__((ext_vector_type(2))) unsigned int u32x2;
typedef __attribute__((ext_vector_type(4))) unsigned int u32x4;

#define SLAB 9216      // bytes per slab: 144 rows x 64B (32 bf16)

// involution swizzle: XOR bank-group bits (4-5) with row bits (7-8)
__device__ __forceinline__ unsigned sw(unsigned off) {
  return off ^ (((off >> 7) & 3u) << 4);
}

__device__ __forceinline__ unsigned pk2(float lo, float hi) {
  union { __hip_bfloat162 h; unsigned u; } c;
  c.h = __float22bfloat162_rn(float2{lo, hi});
  return c.u;
}

// one-time: ker (fp32, N*K x F x C) -> bf16 fragment-linear in ws
// frag(ch,nk,ft,lane) holds W[f=ft*16+(lane&15), c=ch*32+(lane>>4)*8 .. +8]
extern "C" __global__ void w_prep(const float* __restrict__ ker, u32x4* __restrict__ wsw) {
  const int nk = blockIdx.x % 36;
  const int ch = blockIdx.x / 36;
  const int lane = threadIdx.x & 63;
  const int ft = threadIdx.x >> 6;
  const float* src = ker + (size_t)(nk * 64 + ft * 16 + (lane & 15)) * 64
                         + ch * 32 + (lane >> 4) * 8;
  f32x4 a0 = *(const f32x4*)src;
  f32x4 a1 = *(const f32x4*)(src + 4);
  u32x4 h = { pk2(a0.x, a0.y), pk2(a0.z, a0.w), pk2(a1.x, a1.y), pk2(a1.z, a1.w) };
  wsw[((ch * 36 + nk) * 4 + ft) * 64 + lane] = h;
}

// one k-iteration (fat wave): issue replacement W loads (window +3, all 4 f-tiles),
// 2 B ds_reads (this wave's 2 col-tiles), setprio-wrapped 8-MFMA cluster, rotate.
#define KSTEP(KK, WREG, S2, K2) do {                                           \
    const int _wo = (((S2) & 1) * 9216) + (((S2) >> 1) * 2304) + ((K2) * 256); \
    short8 _n0 = wqb[_wo];                                                     \
    short8 _n1 = wqb[_wo + 64];                                                \
    short8 _n2 = wqb[_wo + 128];                                               \
    short8 _n3 = wqb[_wo + 192];                                               \
    const unsigned _kq = cb + (unsigned)(((KK) >> 2) * 512) + poff[(KK) & 3];  \
    short8 _b0 = *(const short8*)(xs + _kq);                                   \
    short8 _b1 = *(const short8*)(xs + _kq + 1024u);                           \
    __builtin_amdgcn_s_setprio(1);                                             \
    acc[0][0] = __builtin_amdgcn_mfma_f32_16x16x32_bf16(WREG[0], _b0, acc[0][0], 0, 0, 0); \
    acc[1][0] = __builtin_amdgcn_mfma_f32_16x16x32_bf16(WREG[1], _b0, acc[1][0], 0, 0, 0); \
    acc[2][0] = __builtin_amdgcn_mfma_f32_16x16x32_bf16(WREG[2], _b0, acc[2][0], 0, 0, 0); \
    acc[3][0] = __builtin_amdgcn_mfma_f32_16x16x32_bf16(WREG[3], _b0, acc[3][0], 0, 0, 0); \
    acc[0][1] = __builtin_amdgcn_mfma_f32_16x16x32_bf16(WREG[0], _b1, acc[0][1], 0, 0, 0); \
    acc[1][1] = __builtin_amdgcn_mfma_f32_16x16x32_bf16(WREG[1], _b1, acc[1][1], 0, 0, 0); \
    acc[2][1] = __builtin_amdgcn_mfma_f32_16x16x32_bf16(WREG[2], _b1, acc[2][1], 0, 0, 0); \
    acc[3][1] = __builtin_amdgcn_mfma_f32_16x16x32_bf16(WREG[3], _b1, acc[3][1], 0, 0, 0); \
    __builtin_amdgcn_s_setprio(0);                                             \
    WREG[0] = _n0; WREG[1] = _n1; WREG[2] = _n2; WREG[3] = _n3;                \
  } while (0)

extern "C" __global__ __launch_bounds__(256, 3)
void glc_mfma(const float* __restrict__ x, const short8* __restrict__ wsw,
              const int* __restrict__ nb, float* __restrict__ out) {
  __shared__ __align__(16) char xs[2 * SLAB];

  const int bid = blockIdx.x;
  const int tt = bid % 5;
  const int u  = (bid / 5) % 25;
  const int a  = (bid / 125) % 3;
  const int b  = bid / 375;
  const int t0 = tt * 64;

  const int tid  = threadIdx.x;
  const int lane = tid & 63;
  const int wave = tid >> 6;           // 0..3: owns col-tiles {2*wave, 2*wave+1}, ALL 64 f

  const int rl = lane & 15, gq = lane >> 4;
  unsigned poff[4];
#pragma unroll
  for (int m = 0; m < 4; ++m)
    poff[m] = sw((unsigned)((2 * m + rl) * 64 + gq * 16));

  f32x4 acc[4][2];
#pragma unroll
  for (int j = 0; j < 4; ++j)
#pragma unroll
    for (int i = 0; i < 2; ++i) acc[j][i] = (f32x4){0.f, 0.f, 0.f, 0.f};

  // ---- per-thread staging load offsets (1152 f32x4 over 256 threads) ----
  int goff[5];
#pragma unroll
  for (int j = 0; j < 5; ++j) {
    const int idx = j * 256 + tid;      // 0..1151 used (j=4 active only for tid<128)
    const int r = idx >> 3;             // row (t-clamp bounds inactive lanes too)
    const int q = idx & 7;
    int t = t0 + (r >> 1); if (t > 299) t = 299;   // clamp; garbage discarded
    goff[j] = t * 9600 + (r & 1) * 64 + q * 4;     // x fp32 offset (v,ch terms per step)
  }
  const float* xb = x + (size_t)b * (300 * 9600) + (size_t)a * 3200;
  const short8* wqb = wsw + lane;
  const int* nbu = nb + u * 4;

  f32x4 sr[5];
  auto stage_load = [&](int snx) {
    const int add = nbu[snx >> 1] * 128 + (snx & 1) * 32;
#pragma unroll
    for (int j = 0; j < 5; ++j)
      if (j < 4 || tid < 128)
        sr[j] = *(const f32x4*)(xb + goff[j] + add);
  };
  auto stage_write = [&](int snx) {
    char* dst = xs + (snx & 1) * SLAB;
#pragma unroll
    for (int j = 0; j < 5; ++j)
      if (j < 4 || tid < 128) {
        const int idx = j * 256 + tid;
        const int r = idx >> 3, q = idx & 7;
        u32x2 h = { pk2(sr[j].x, sr[j].y), pk2(sr[j].z, sr[j].w) };
        *(u32x2*)(dst + sw((unsigned)(r * 64 + q * 8))) = h;
      }
  };

  // ---- prologue: W(0, k=0..2) into 3-deep window (4 f-tiles each); stage step 0 ----
  short8 wA[4], wB[4], wC[4];
#pragma unroll
  for (int j = 0; j < 4; ++j) {
    wA[j] = wqb[0 * 256 + j * 64];
    wB[j] = wqb[1 * 256 + j * 64];
    wC[j] = wqb[2 * 256 + j * 64];
  }
  stage_load(0);
  stage_write(0);
  __syncthreads();

  // ---- main loop: 8 steps of (n = s>>1, ch = s&1) ----
#pragma unroll 1
  for (int s = 0; s < 8; ++s) {
    const int sn = (s < 7) ? (s + 1) : 7;      // s=7: dummy in-bounds reloads
    if (s < 7) stage_load(s + 1);              // HBM loads overlap compute
    const unsigned cb = (unsigned)((s & 1) * SLAB + wave * 2048);
    KSTEP(0, wA, s, 3);  KSTEP(1, wB, s, 4);  KSTEP(2, wC, s, 5);
    KSTEP(3, wA, s, 6);  KSTEP(4, wB, s, 7);  KSTEP(5, wC, s, 8);
    KSTEP(6, wA, sn, 0); KSTEP(7, wB, sn, 1); KSTEP(8, wC, sn, 2);
    if (s < 7) {
      stage_write(s + 1);                      // vmcnt wait lands after compute
      __syncthreads();
    }
  }

  // ---- epilogue: col = (wave*2+i)*16+rl; f = ft*16 + gq*4 + reg; full 256B rows ----
  const f32x4 z4 = (f32x4){0.f, 0.f, 0.f, 0.f};
#pragma unroll
  for (int i = 0; i < 2; ++i) {
    const int col = (wave * 2 + i) * 16 + rl;  // 0..127 within u (t-rel, p-minor)
    const int t = t0 + (col >> 1);
    const int p = col & 1;
    if (t < 300) {
      float* dst = out + ((size_t)((b * 300 + t) * 3 + a) * 50 + (u * 2 + p)) * 64 + gq * 4;
      const bool valid = (t < 292);     // t>=292: zero-pad tail
#pragma unroll
      for (int ft = 0; ft < 4; ++ft) {
        f32x4 v = valid ? acc[ft][i] : z4;
        __builtin_nontemporal_store(v, (f32x4*)(dst + ft * 16));
      }
    }
  }
}

extern "C" void kernel_launch(void* const* d_in, const int* in_sizes, int n_in,
                              void* d_out, int out_size, void* d_ws, size_t ws_size,
                              hipStream_t stream) {
  const float* x   = (const float*)d_in[0];
  const float* ker = (const float*)d_in[1];
  const int*   nb  = (const int*)d_in[2];
  float* out = (float*)d_out;

  w_prep<<<dim3(72), dim3(256), 0, stream>>>(ker, (u32x4*)d_ws);
  // grid: 5 t-tiles * 25 u * 3 a * 8 b = 3000 independent 4-wave blocks
  glc_mfma<<<dim3(3000), dim3(256), 0, stream>>>(x, (const short8*)d_ws, nb, out);
}